// Round 3
// baseline (474.446 us; speedup 1.0000x reference)
//
#include <hip/hip_runtime.h>
#include <stdint.h>

#define NB 16
#define NL 4096
#define ND 1024

// ---------------------------------------------------------------------------
// Exact JAX threefry2x32 (20 rounds), matching jax/_src/prng.py.
// Hand-verified vs Random123 KAT: key=(0,0), ctr=(0,0) -> (0x6B200159, 0x99BA4EFE).
// key = jax.random.key(42) -> (k0, k1) = (0, 42)
// ---------------------------------------------------------------------------
__device__ __forceinline__ uint32_t rotl32(uint32_t x, uint32_t r) {
    return (x << r) | (x >> (32u - r));
}

__device__ __forceinline__ void threefry2x32(uint32_t k0, uint32_t k1,
                                             uint32_t x0, uint32_t x1,
                                             uint32_t& o0, uint32_t& o1) {
    uint32_t k2 = k0 ^ k1 ^ 0x1BD11BDAu;
    x0 += k0; x1 += k1;
    // group 1: rotations {13,15,26,6}, inject (k1, k2+1)
    x0 += x1; x1 = rotl32(x1, 13); x1 ^= x0;
    x0 += x1; x1 = rotl32(x1, 15); x1 ^= x0;
    x0 += x1; x1 = rotl32(x1, 26); x1 ^= x0;
    x0 += x1; x1 = rotl32(x1, 6);  x1 ^= x0;
    x0 += k1; x1 += k2 + 1u;
    // group 2: {17,29,16,24}, inject (k2, k0+2)
    x0 += x1; x1 = rotl32(x1, 17); x1 ^= x0;
    x0 += x1; x1 = rotl32(x1, 29); x1 ^= x0;
    x0 += x1; x1 = rotl32(x1, 16); x1 ^= x0;
    x0 += x1; x1 = rotl32(x1, 24); x1 ^= x0;
    x0 += k2; x1 += k0 + 2u;
    // group 3: {13,15,26,6}, inject (k0, k1+3)
    x0 += x1; x1 = rotl32(x1, 13); x1 ^= x0;
    x0 += x1; x1 = rotl32(x1, 15); x1 ^= x0;
    x0 += x1; x1 = rotl32(x1, 26); x1 ^= x0;
    x0 += x1; x1 = rotl32(x1, 6);  x1 ^= x0;
    x0 += k0; x1 += k1 + 3u;
    // group 4: {17,29,16,24}, inject (k1, k2+4)
    x0 += x1; x1 = rotl32(x1, 17); x1 ^= x0;
    x0 += x1; x1 = rotl32(x1, 29); x1 ^= x0;
    x0 += x1; x1 = rotl32(x1, 16); x1 ^= x0;
    x0 += x1; x1 = rotl32(x1, 24); x1 ^= x0;
    x0 += k1; x1 += k2 + 4u;
    // group 5: {13,15,26,6}, inject (k2, k0+5)
    x0 += x1; x1 = rotl32(x1, 13); x1 ^= x0;
    x0 += x1; x1 = rotl32(x1, 15); x1 ^= x0;
    x0 += x1; x1 = rotl32(x1, 26); x1 ^= x0;
    x0 += x1; x1 = rotl32(x1, 6);  x1 ^= x0;
    x0 += k2; x1 += k0 + 5u;
    o0 = x0; o1 = x1;
}

// ---------------------------------------------------------------------------
// Per-row key generation + stable bitonic argsort (one block per batch row).
//
// JAX >= 0.4.30 defaults jax_threefry_partitionable=True: random_bits uses a
// PER-ELEMENT 64-bit counter g, counter pair (x0,x1) = (g>>32, g) = (0, g)
// for g < 2^32, and the 32-bit output is o0 ^ o1 (both lanes XOR-folded).
// (Round 1 used the legacy iota-split scheme -> wrong permutation.)
//
// Stability: composite uint64 key = (float_bits << 16) | index. All key floats
// are in [0, 2), so the positive-float bit pattern is order-preserving; index
// in the low bits breaks ties ascending == stable argsort semantics.
// ---------------------------------------------------------------------------
__global__ __launch_bounds__(1024) void keys_sort_kernel(
        const int* __restrict__ mask, int* __restrict__ perm_ws,
        float* __restrict__ perm_out) {
    __shared__ unsigned long long keys[NL];
    const int b = blockIdx.x;
    const int tid = threadIdx.x;

    #pragma unroll
    for (int t = 0; t < 4; ++t) {
        const int l = t * 1024 + tid;
        const int g = b * NL + l;           // flat counter index, row-major
        uint32_t o0, o1;
        threefry2x32(0u, 42u, 0u, (uint32_t)g, o0, o1);  // ctr pair (0, g)
        const uint32_t bits = o0 ^ o1;                   // partitionable fold
        const float u = __uint_as_float((bits >> 9) | 0x3F800000u) - 1.0f;
        const float keyf = (mask[g] == 1) ? u
                                          : (1.0f + (float)l * (1.0f / (float)NL));
        const uint32_t kb = __float_as_uint(keyf);
        keys[l] = (((unsigned long long)kb) << 16) | (unsigned long long)l;
    }
    __syncthreads();

    // Bitonic sort, ascending. n = 4096, 12*13/2 = 78 steps.
    for (int k = 2; k <= NL; k <<= 1) {
        for (int j = k >> 1; j > 0; j >>= 1) {
            #pragma unroll
            for (int t = 0; t < 4; ++t) {
                const int i = t * 1024 + tid;
                const int p = i ^ j;
                if (p > i) {
                    const bool asc = ((i & k) == 0);
                    const unsigned long long a = keys[i];
                    const unsigned long long c = keys[p];
                    if (asc ? (a > c) : (a < c)) {
                        keys[i] = c;
                        keys[p] = a;
                    }
                }
            }
            __syncthreads();
        }
    }

    #pragma unroll
    for (int t = 0; t < 4; ++t) {
        const int i = t * 1024 + tid;
        const int pv = (int)(keys[i] & 0xFFFFull);
        perm_ws[b * NL + i]  = pv;
        perm_out[b * NL + i] = (float)pv;   // perm emitted as float per harness
    }
}

// ---------------------------------------------------------------------------
// Gather: out[b, i, :] = x[b, perm[b,i], :].  One block per output row,
// 256 threads x float4 = 1024 floats.  Fully coalesced read and write.
// ---------------------------------------------------------------------------
__global__ __launch_bounds__(256) void gather_kernel(
        const float* __restrict__ x, const int* __restrict__ perm,
        float* __restrict__ out) {
    const int row = blockIdx.x;        // 0 .. NB*NL-1
    const int b = row >> 12;           // row / NL
    const int src = perm[row];
    const float4* __restrict__ sp =
        (const float4*)(x + ((size_t)b * NL + (size_t)src) * ND);
    float4* __restrict__ dp = (float4*)(out + (size_t)row * ND);
    dp[threadIdx.x] = sp[threadIdx.x];
}

extern "C" void kernel_launch(void* const* d_in, const int* in_sizes, int n_in,
                              void* d_out, int out_size, void* d_ws, size_t ws_size,
                              hipStream_t stream) {
    const float* x    = (const float*)d_in[0];
    const int*   mask = (const int*)d_in[1];
    float* out      = (float*)d_out;
    float* perm_out = out + (size_t)NB * NL * ND;  // x_perm first, then perm
    int*   perm_ws  = (int*)d_ws;                  // 16*4096*4 = 256 KiB scratch

    hipLaunchKernelGGL(keys_sort_kernel, dim3(NB), dim3(1024), 0, stream,
                       mask, perm_ws, perm_out);
    hipLaunchKernelGGL(gather_kernel, dim3(NB * NL), dim3(256), 0, stream,
                       x, perm_ws, out);
}